// Round 1
// baseline (7590.719 us; speedup 1.0000x reference)
//
#include <hip/hip_runtime.h>
#include <math.h>

#define HID  128
#define EDIM 4
#define NE   8   // edges per block
#define NN   8   // nodes per block

__device__ __forceinline__ float silu_f(float v) {
    return v / (1.0f + __expf(-v));
}

// x[i][:] = emb[z[i]][:]
__global__ __launch_bounds__(HID) void embed_kernel(const int* __restrict__ z,
        const float* __restrict__ emb, float* __restrict__ x, int n) {
    int i = blockIdx.x;
    if (i >= n) return;
    int t = threadIdx.x;
    x[(size_t)i * HID + t] = emb[(size_t)z[i] * HID + t];
}

// Per-edge 2-layer MLP + scatter-add into agg.
// Block = 128 threads (one per output column), NE edges per block.
__global__ __launch_bounds__(HID) void edge_kernel(
        const float* __restrict__ x, const int* __restrict__ src,
        const int* __restrict__ dst, const float* __restrict__ ea,
        const float* __restrict__ w1, const float* __restrict__ b1,
        const float* __restrict__ w2, const float* __restrict__ b2,
        float* __restrict__ agg, int nE) {
    __shared__ float m_in[NE][264];   // 260 used, 264 keeps rows 16B-aligned
    __shared__ float hbuf[NE][HID];
    const int e0 = blockIdx.x * NE;
    const int t  = threadIdx.x;
    int dcache[NE];

    #pragma unroll
    for (int e = 0; e < NE; ++e) {
        int ee = e0 + e;
        if (ee < nE) {
            int s = src[ee], d = dst[ee];
            dcache[e] = d;
            m_in[e][t]        = x[(size_t)s * HID + t];
            m_in[e][HID + t]  = x[(size_t)d * HID + t];
            if (t < EDIM) m_in[e][2 * HID + t] = ea[(size_t)ee * EDIM + t];
        } else {
            dcache[e] = 0;
            m_in[e][t] = 0.f; m_in[e][HID + t] = 0.f;
            if (t < EDIM) m_in[e][2 * HID + t] = 0.f;
        }
    }
    __syncthreads();

    float acc[NE];
    {
        float bias = b1[t];
        #pragma unroll
        for (int e = 0; e < NE; ++e) acc[e] = bias;
    }
    // [NE,260] @ [260,128]: weight load amortized over NE fmas; m_in via b128 broadcast
    for (int k4 = 0; k4 < 65; ++k4) {
        float4 mv[NE];
        #pragma unroll
        for (int e = 0; e < NE; ++e) mv[e] = *(const float4*)&m_in[e][k4 * 4];
        #pragma unroll
        for (int j = 0; j < 4; ++j) {
            float w = w1[(size_t)(k4 * 4 + j) * HID + t];
            #pragma unroll
            for (int e = 0; e < NE; ++e)
                acc[e] += ((const float*)&mv[e])[j] * w;
        }
    }
    #pragma unroll
    for (int e = 0; e < NE; ++e) hbuf[e][t] = silu_f(acc[e]);
    __syncthreads();

    {
        float bias = b2[t];
        #pragma unroll
        for (int e = 0; e < NE; ++e) acc[e] = bias;
    }
    for (int k4 = 0; k4 < 32; ++k4) {
        float4 mv[NE];
        #pragma unroll
        for (int e = 0; e < NE; ++e) mv[e] = *(const float4*)&hbuf[e][k4 * 4];
        #pragma unroll
        for (int j = 0; j < 4; ++j) {
            float w = w2[(size_t)(k4 * 4 + j) * HID + t];
            #pragma unroll
            for (int e = 0; e < NE; ++e)
                acc[e] += ((const float*)&mv[e])[j] * w;
        }
    }
    #pragma unroll
    for (int e = 0; e < NE; ++e) {
        int ee = e0 + e;
        if (ee < nE)
            atomicAdd(&agg[(size_t)dcache[e] * HID + t], silu_f(acc[e]));
    }
}

// x[i] = silu(concat(x[i], agg[i]) @ nw + nb), in place (block owns its rows)
__global__ __launch_bounds__(HID) void node_kernel(
        float* __restrict__ x, const float* __restrict__ agg,
        const float* __restrict__ nw, const float* __restrict__ nb, int n) {
    __shared__ float nin[NN][2 * HID];
    const int i0 = blockIdx.x * NN;
    const int t  = threadIdx.x;
    #pragma unroll
    for (int e = 0; e < NN; ++e) {
        int i = i0 + e;
        if (i < n) {
            nin[e][t]       = x[(size_t)i * HID + t];
            nin[e][HID + t] = agg[(size_t)i * HID + t];
        } else { nin[e][t] = 0.f; nin[e][HID + t] = 0.f; }
    }
    __syncthreads();

    float acc[NN];
    {
        float bias = nb[t];
        #pragma unroll
        for (int e = 0; e < NN; ++e) acc[e] = bias;
    }
    for (int k4 = 0; k4 < 64; ++k4) {
        float4 mv[NN];
        #pragma unroll
        for (int e = 0; e < NN; ++e) mv[e] = *(const float4*)&nin[e][k4 * 4];
        #pragma unroll
        for (int j = 0; j < 4; ++j) {
            float w = nw[(size_t)(k4 * 4 + j) * HID + t];
            #pragma unroll
            for (int e = 0; e < NN; ++e)
                acc[e] += ((const float*)&mv[e])[j] * w;
        }
    }
    #pragma unroll
    for (int e = 0; e < NN; ++e) {
        int i = i0 + e;
        if (i < n) x[(size_t)i * HID + t] = silu_f(acc[e]);
    }
}

// per-graph sums + counts via atomics (batch is arbitrary here; sortedness unused)
__global__ __launch_bounds__(HID) void segsum_kernel(
        const float* __restrict__ x, const int* __restrict__ batch,
        float* __restrict__ sums, float* __restrict__ counts, int n) {
    int i = blockIdx.x;
    if (i >= n) return;
    int t = threadIdx.x;
    int b = batch[i];
    atomicAdd(&sums[(size_t)b * HID + t], x[(size_t)i * HID + t]);
    if (t == 0) atomicAdd(&counts[b], 1.0f);
}

// pred[g] = silu(g @ rw1 + rb1) @ rw2 + rb2, one block per graph
__global__ __launch_bounds__(HID) void readout_kernel(
        const float* __restrict__ sums, const float* __restrict__ counts,
        const float* __restrict__ rw1, const float* __restrict__ rb1,
        const float* __restrict__ rw2, const float* __restrict__ rb2,
        float* __restrict__ pred) {
    __shared__ float gv[HID];
    __shared__ float hv[HID];
    const int g = blockIdx.x;
    const int t = threadIdx.x;
    float c = counts[g];
    if (c < 1.0f) c = 1.0f;
    gv[t] = sums[(size_t)g * HID + t] / c;
    __syncthreads();
    float acc = rb1[t];
    for (int k4 = 0; k4 < 32; ++k4) {
        float4 mv = *(const float4*)&gv[k4 * 4];
        #pragma unroll
        for (int j = 0; j < 4; ++j)
            acc += ((const float*)&mv)[j] * rw1[(size_t)(k4 * 4 + j) * HID + t];
    }
    hv[t] = silu_f(acc) * rw2[t];
    __syncthreads();
    for (int s = HID / 2; s > 0; s >>= 1) {
        if (t < s) hv[t] += hv[t + s];
        __syncthreads();
    }
    if (t == 0) pred[g] = hv[0] + rb2[0];
}

extern "C" void kernel_launch(void* const* d_in, const int* in_sizes, int n_in,
                              void* d_out, int out_size, void* d_ws, size_t ws_size,
                              hipStream_t stream) {
    const int*   z          = (const int*)d_in[0];
    const int*   edge_index = (const int*)d_in[1];
    const float* edge_attr  = (const float*)d_in[2];
    const int*   batch      = (const int*)d_in[3];
    const float* emb        = (const float*)d_in[4];
    const float* ew1        = (const float*)d_in[5];
    const float* eb1        = (const float*)d_in[6];
    const float* ew2        = (const float*)d_in[7];
    const float* eb2        = (const float*)d_in[8];
    const float* nw         = (const float*)d_in[9];
    const float* nb         = (const float*)d_in[10];
    const float* rw1        = (const float*)d_in[11];
    const float* rb1        = (const float*)d_in[12];
    const float* rw2        = (const float*)d_in[13];
    const float* rb2        = (const float*)d_in[14];
    float* pred = (float*)d_out;

    const int N = in_sizes[0];
    const int E = in_sizes[1] / 2;
    const int G = out_size;           // 512
    const int* srcI = edge_index;     // edge_index[0]
    const int* dstI = edge_index + E; // edge_index[1]

    float* x      = (float*)d_ws;
    float* agg    = x + (size_t)N * HID;
    float* sums   = agg + (size_t)N * HID;
    float* counts = sums + (size_t)G * HID;

    embed_kernel<<<N, HID, 0, stream>>>(z, emb, x, N);

    for (int l = 0; l < 4; ++l) {
        hipMemsetAsync(agg, 0, (size_t)N * HID * sizeof(float), stream);
        edge_kernel<<<(E + NE - 1) / NE, HID, 0, stream>>>(
            x, srcI, dstI, edge_attr,
            ew1 + (size_t)l * (2 * HID + EDIM) * HID,
            eb1 + (size_t)l * HID,
            ew2 + (size_t)l * HID * HID,
            eb2 + (size_t)l * HID,
            agg, E);
        node_kernel<<<(N + NN - 1) / NN, HID, 0, stream>>>(
            x, agg,
            nw + (size_t)l * 2 * HID * HID,
            nb + (size_t)l * HID, N);
    }

    hipMemsetAsync(sums,   0, (size_t)G * HID * sizeof(float), stream);
    hipMemsetAsync(counts, 0, (size_t)G * sizeof(float), stream);
    segsum_kernel<<<N, HID, 0, stream>>>(x, batch, sums, counts, N);
    readout_kernel<<<G, HID, 0, stream>>>(sums, counts, rw1, rb1, rw2, rb2, pred);
}

// Round 2
// 1760.317 us; speedup vs baseline: 4.3121x; 4.3121x over previous
//
#include <hip/hip_runtime.h>
#include <math.h>

#define HID  128
#define EDIM 4

typedef unsigned short u16;
typedef u16    us8   __attribute__((ext_vector_type(8)));
typedef __bf16 bf16x8 __attribute__((ext_vector_type(8)));
typedef float  f32x4 __attribute__((ext_vector_type(4)));

__device__ __forceinline__ float silu_f(float v) {
    return v / (1.0f + __expf(-v));
}
__device__ __forceinline__ u16 f2bf(float f) {   // RNE fp32->bf16
    unsigned u = __float_as_uint(f);
    unsigned r = u + 0x7fffu + ((u >> 16) & 1u);
    return (u16)(r >> 16);
}
__device__ __forceinline__ float bf2f(u16 s) {
    return __uint_as_float(((unsigned)s) << 16);
}

// ---------------- prep kernels (run every call; ws is re-poisoned) ----------

// Swizzle weights [L][K][128] fp32 -> MFMA B-fragments bf16:
// out[((l*KT*8 + kt*8+nt)*64 + lane)*8 + j] = W[l][kt*32+(lane>>4)*8+j][nt*16+(lane&15)]
__global__ __launch_bounds__(256) void prep_wfrag(const float* __restrict__ w,
        u16* __restrict__ out, int KT, int K, int total) {
    int idx = blockIdx.x * 256 + threadIdx.x;
    if (idx >= total) return;
    int lane = idx & 63;
    int f    = (idx >> 6) % (KT * 8);
    int l    = idx / (64 * KT * 8);
    int kt = f >> 3, nt = f & 7;
    int n  = nt * 16 + (lane & 15);
    int k0 = kt * 32 + ((lane >> 4) * 8);
    us8 v;
    #pragma unroll
    for (int j = 0; j < 8; ++j) {
        int k = k0 + j;
        v[j] = (k < K) ? f2bf(w[((size_t)l * K + k) * HID + n]) : (u16)0;
    }
    *(us8*)&out[((size_t)(l * KT * 8 + f) * 64 + lane) * 8] = v;
}

__global__ __launch_bounds__(256) void prep_ea(const float* __restrict__ ea,
        u16* __restrict__ eab, int total) {
    int i = blockIdx.x * 256 + threadIdx.x;
    if (i < total) eab[i] = f2bf(ea[i]);
}

// x_bf16[i][:] = bf16(emb[z[i]][:])
__global__ __launch_bounds__(HID) void embed_kernel(const int* __restrict__ z,
        const float* __restrict__ emb, u16* __restrict__ xb, int n) {
    int i = blockIdx.x;
    if (i >= n) return;
    int t = threadIdx.x;
    xb[(size_t)i * HID + t] = f2bf(emb[(size_t)z[i] * HID + t]);
}

// ---------------- edge MLP: MFMA, 32 edges/block, 256 threads ---------------
// A[32 x 288pad296] = [x_src | x_dst | ea | 0], GEMM1 -> silu -> H[32x128pad136]
// GEMM2 -> silu -> atomic scatter into agg (fp32)
__global__ __launch_bounds__(256) void edge_mfma(
        const u16* __restrict__ xb, const int* __restrict__ src,
        const int* __restrict__ dst, const u16* __restrict__ eab,
        const u16* __restrict__ w1f, const float* __restrict__ b1,
        const u16* __restrict__ w2f, const float* __restrict__ b2,
        float* __restrict__ agg, int nE) {
    __shared__ u16 A[32 * 296];   // stride 296 bf16 = 148 dwords %32=20 -> conflict-free b128
    __shared__ u16 H[32 * 136];   // stride 136 bf16 = 68 dwords %32=4  -> conflict-free b128
    __shared__ int dsh[32];
    const int t  = threadIdx.x;
    const int e0 = blockIdx.x * 32;

    #pragma unroll
    for (int it = 0; it < 4; ++it) {             // 32 rows x 32 chunks of 8 bf16
        int slot = it * 256 + t;
        int row = slot >> 5, ch = slot & 31;
        int e = e0 + row;
        us8 v;
        if (e < nE) {
            int node = (ch < 16) ? src[e] : dst[e];
            v = *(const us8*)&xb[(size_t)node * HID + (ch & 15) * 8];
        } else {
            #pragma unroll
            for (int j = 0; j < 8; ++j) v[j] = 0;
        }
        *(us8*)&A[row * 296 + ch * 8] = v;       // ch*8 covers cols 0..255
    }
    if (t < 32) {
        int e = e0 + t;
        dsh[t] = (e < nE) ? dst[e] : 0;
        int base = t * 296 + 256;
        if (e < nE) {
            const u16* p = &eab[(size_t)e * EDIM];
            A[base + 0] = p[0]; A[base + 1] = p[1];
            A[base + 2] = p[2]; A[base + 3] = p[3];
        } else {
            A[base + 0] = 0; A[base + 1] = 0; A[base + 2] = 0; A[base + 3] = 0;
        }
        #pragma unroll
        for (int j = 4; j < 32; ++j) A[base + j] = 0;   // zero K-pad 260..287
    }
    __syncthreads();

    const int wv = t >> 6, lane = t & 63;
    const int lrow = lane & 15;          // A-row / C-col low bits
    const int kq   = (lane >> 4) * 8;    // k offset within K-tile
    const int rq   = (lane >> 4) * 4;    // C-row quad base

    f32x4 acc[2][2];
    {
        float bias0 = b1[wv * 32 + lrow], bias1 = b1[wv * 32 + 16 + lrow];
        #pragma unroll
        for (int r = 0; r < 4; ++r) {
            acc[0][0][r] = bias0; acc[1][0][r] = bias0;
            acc[0][1][r] = bias1; acc[1][1][r] = bias1;
        }
    }
    #pragma unroll
    for (int kt = 0; kt < 9; ++kt) {
        bf16x8 a0 = *(const bf16x8*)&A[lrow * 296 + kt * 32 + kq];
        bf16x8 a1 = *(const bf16x8*)&A[(16 + lrow) * 296 + kt * 32 + kq];
        bf16x8 w0 = *(const bf16x8*)&w1f[((size_t)(kt * 8 + wv * 2 + 0) * 64 + lane) * 8];
        bf16x8 w1 = *(const bf16x8*)&w1f[((size_t)(kt * 8 + wv * 2 + 1) * 64 + lane) * 8];
        acc[0][0] = __builtin_amdgcn_mfma_f32_16x16x32_bf16(a0, w0, acc[0][0], 0, 0, 0);
        acc[0][1] = __builtin_amdgcn_mfma_f32_16x16x32_bf16(a0, w1, acc[0][1], 0, 0, 0);
        acc[1][0] = __builtin_amdgcn_mfma_f32_16x16x32_bf16(a1, w0, acc[1][0], 0, 0, 0);
        acc[1][1] = __builtin_amdgcn_mfma_f32_16x16x32_bf16(a1, w1, acc[1][1], 0, 0, 0);
    }
    #pragma unroll
    for (int mt = 0; mt < 2; ++mt)
        #pragma unroll
        for (int ntl = 0; ntl < 2; ++ntl)
            #pragma unroll
            for (int r = 0; r < 4; ++r) {
                int row = mt * 16 + rq + r;
                int col = wv * 32 + ntl * 16 + lrow;
                H[row * 136 + col] = f2bf(silu_f(acc[mt][ntl][r]));
            }
    __syncthreads();

    f32x4 acc2[2][2];
    {
        float bias0 = b2[wv * 32 + lrow], bias1 = b2[wv * 32 + 16 + lrow];
        #pragma unroll
        for (int r = 0; r < 4; ++r) {
            acc2[0][0][r] = bias0; acc2[1][0][r] = bias0;
            acc2[0][1][r] = bias1; acc2[1][1][r] = bias1;
        }
    }
    #pragma unroll
    for (int kt = 0; kt < 4; ++kt) {
        bf16x8 a0 = *(const bf16x8*)&H[lrow * 136 + kt * 32 + kq];
        bf16x8 a1 = *(const bf16x8*)&H[(16 + lrow) * 136 + kt * 32 + kq];
        bf16x8 w0 = *(const bf16x8*)&w2f[((size_t)(kt * 8 + wv * 2 + 0) * 64 + lane) * 8];
        bf16x8 w1 = *(const bf16x8*)&w2f[((size_t)(kt * 8 + wv * 2 + 1) * 64 + lane) * 8];
        acc2[0][0] = __builtin_amdgcn_mfma_f32_16x16x32_bf16(a0, w0, acc2[0][0], 0, 0, 0);
        acc2[0][1] = __builtin_amdgcn_mfma_f32_16x16x32_bf16(a0, w1, acc2[0][1], 0, 0, 0);
        acc2[1][0] = __builtin_amdgcn_mfma_f32_16x16x32_bf16(a1, w0, acc2[1][0], 0, 0, 0);
        acc2[1][1] = __builtin_amdgcn_mfma_f32_16x16x32_bf16(a1, w1, acc2[1][1], 0, 0, 0);
    }
    #pragma unroll
    for (int mt = 0; mt < 2; ++mt)
        #pragma unroll
        for (int ntl = 0; ntl < 2; ++ntl)
            #pragma unroll
            for (int r = 0; r < 4; ++r) {
                int row = mt * 16 + rq + r;
                if (e0 + row < nE) {
                    int col = wv * 32 + ntl * 16 + lrow;
                    atomicAdd(&agg[(size_t)dsh[row] * HID + col],
                              silu_f(acc2[mt][ntl][r]));
                }
            }
}

// ---------------- node MLP: MFMA, 32 nodes/block ----------------------------
// A[32 x 256pad264] = [x_bf16 | bf16(agg)]; x = silu(A @ nw + nb) in place
__global__ __launch_bounds__(256) void node_mfma(
        u16* __restrict__ xb, const float* __restrict__ agg,
        const u16* __restrict__ nwf, const float* __restrict__ nb, int n) {
    __shared__ u16 A[32 * 264];   // 264 bf16 = 132 dwords %32=4 -> conflict-free
    const int t  = threadIdx.x;
    const int i0 = blockIdx.x * 32;

    #pragma unroll
    for (int it = 0; it < 2; ++it) {             // x part: 32 rows x 16 chunks
        int slot = it * 256 + t;
        int row = slot >> 4, ch = slot & 15;
        int i = i0 + row;
        us8 v;
        if (i < n) v = *(const us8*)&xb[(size_t)i * HID + ch * 8];
        else { 
            #pragma unroll
            for (int j = 0; j < 8; ++j) v[j] = 0;
        }
        *(us8*)&A[row * 264 + ch * 8] = v;
    }
    #pragma unroll
    for (int it = 0; it < 4; ++it) {             // agg part: 32 rows x 32 quads
        int slot = it * 256 + t;
        int row = slot >> 5, q = slot & 31;
        int i = i0 + row;
        float4 v = make_float4(0.f, 0.f, 0.f, 0.f);
        if (i < n) v = *(const float4*)&agg[(size_t)i * HID + q * 4];
        int base = row * 264 + HID + q * 4;
        A[base + 0] = f2bf(v.x); A[base + 1] = f2bf(v.y);
        A[base + 2] = f2bf(v.z); A[base + 3] = f2bf(v.w);
    }
    __syncthreads();

    const int wv = t >> 6, lane = t & 63;
    const int lrow = lane & 15;
    const int kq   = (lane >> 4) * 8;
    const int rq   = (lane >> 4) * 4;

    f32x4 acc[2][2];
    {
        float bias0 = nb[wv * 32 + lrow], bias1 = nb[wv * 32 + 16 + lrow];
        #pragma unroll
        for (int r = 0; r < 4; ++r) {
            acc[0][0][r] = bias0; acc[1][0][r] = bias0;
            acc[0][1][r] = bias1; acc[1][1][r] = bias1;
        }
    }
    #pragma unroll
    for (int kt = 0; kt < 8; ++kt) {
        bf16x8 a0 = *(const bf16x8*)&A[lrow * 264 + kt * 32 + kq];
        bf16x8 a1 = *(const bf16x8*)&A[(16 + lrow) * 264 + kt * 32 + kq];
        bf16x8 w0 = *(const bf16x8*)&nwf[((size_t)(kt * 8 + wv * 2 + 0) * 64 + lane) * 8];
        bf16x8 w1 = *(const bf16x8*)&nwf[((size_t)(kt * 8 + wv * 2 + 1) * 64 + lane) * 8];
        acc[0][0] = __builtin_amdgcn_mfma_f32_16x16x32_bf16(a0, w0, acc[0][0], 0, 0, 0);
        acc[0][1] = __builtin_amdgcn_mfma_f32_16x16x32_bf16(a0, w1, acc[0][1], 0, 0, 0);
        acc[1][0] = __builtin_amdgcn_mfma_f32_16x16x32_bf16(a1, w0, acc[1][0], 0, 0, 0);
        acc[1][1] = __builtin_amdgcn_mfma_f32_16x16x32_bf16(a1, w1, acc[1][1], 0, 0, 0);
    }
    #pragma unroll
    for (int mt = 0; mt < 2; ++mt)
        #pragma unroll
        for (int ntl = 0; ntl < 2; ++ntl)
            #pragma unroll
            for (int r = 0; r < 4; ++r) {
                int row = mt * 16 + rq + r;
                int i = i0 + row;
                if (i < n) {
                    int col = wv * 32 + ntl * 16 + lrow;
                    xb[(size_t)i * HID + col] = f2bf(silu_f(acc[mt][ntl][r]));
                }
            }
}

// ---------------- readout ---------------------------------------------------
__global__ __launch_bounds__(HID) void segsum_kernel(
        const u16* __restrict__ xb, const int* __restrict__ batch,
        float* __restrict__ sums, float* __restrict__ counts, int n) {
    int i = blockIdx.x;
    if (i >= n) return;
    int t = threadIdx.x;
    int b = batch[i];
    atomicAdd(&sums[(size_t)b * HID + t], bf2f(xb[(size_t)i * HID + t]));
    if (t == 0) atomicAdd(&counts[b], 1.0f);
}

__global__ __launch_bounds__(HID) void readout_kernel(
        const float* __restrict__ sums, const float* __restrict__ counts,
        const float* __restrict__ rw1, const float* __restrict__ rb1,
        const float* __restrict__ rw2, const float* __restrict__ rb2,
        float* __restrict__ pred) {
    __shared__ float gv[HID];
    __shared__ float hv[HID];
    const int g = blockIdx.x;
    const int t = threadIdx.x;
    float c = counts[g];
    if (c < 1.0f) c = 1.0f;
    gv[t] = sums[(size_t)g * HID + t] / c;
    __syncthreads();
    float acc = rb1[t];
    for (int k4 = 0; k4 < 32; ++k4) {
        float4 mv = *(const float4*)&gv[k4 * 4];
        #pragma unroll
        for (int j = 0; j < 4; ++j)
            acc += ((const float*)&mv)[j] * rw1[(size_t)(k4 * 4 + j) * HID + t];
    }
    hv[t] = silu_f(acc) * rw2[t];
    __syncthreads();
    for (int s = HID / 2; s > 0; s >>= 1) {
        if (t < s) hv[t] += hv[t + s];
        __syncthreads();
    }
    if (t == 0) pred[g] = hv[0] + rb2[0];
}

extern "C" void kernel_launch(void* const* d_in, const int* in_sizes, int n_in,
                              void* d_out, int out_size, void* d_ws, size_t ws_size,
                              hipStream_t stream) {
    const int*   z          = (const int*)d_in[0];
    const int*   edge_index = (const int*)d_in[1];
    const float* edge_attr  = (const float*)d_in[2];
    const int*   batch      = (const int*)d_in[3];
    const float* emb        = (const float*)d_in[4];
    const float* ew1        = (const float*)d_in[5];
    const float* eb1        = (const float*)d_in[6];
    const float* ew2        = (const float*)d_in[7];
    const float* eb2        = (const float*)d_in[8];
    const float* nw         = (const float*)d_in[9];
    const float* nb         = (const float*)d_in[10];
    const float* rw1        = (const float*)d_in[11];
    const float* rb1        = (const float*)d_in[12];
    const float* rw2        = (const float*)d_in[13];
    const float* rb2        = (const float*)d_in[14];
    float* pred = (float*)d_out;

    const int N = in_sizes[0];
    const int E = in_sizes[1] / 2;
    const int G = out_size;           // 512
    const int* srcI = edge_index;
    const int* dstI = edge_index + E;

    // ---- carve workspace (256B-aligned chunks) ----
    char* base = (char*)d_ws;
    size_t off = 0;
    auto carve = [&](size_t bytes) -> char* {
        char* p = base + off;
        off = (off + bytes + 255) & ~(size_t)255;
        return p;
    };
    float* agg    = (float*)carve((size_t)N * HID * sizeof(float));
    float* sums   = (float*)carve((size_t)G * HID * sizeof(float));
    float* counts = (float*)carve((size_t)G * sizeof(float));
    u16*   xb     = (u16*)carve((size_t)N * HID * sizeof(u16));
    u16*   eab    = (u16*)carve((size_t)E * EDIM * sizeof(u16));
    u16*   w1f    = (u16*)carve((size_t)4 * 72 * 512 * sizeof(u16)); // KT=9
    u16*   w2f    = (u16*)carve((size_t)4 * 32 * 512 * sizeof(u16)); // KT=4
    u16*   nwf    = (u16*)carve((size_t)4 * 64 * 512 * sizeof(u16)); // KT=8

    // ---- prep (must run every call; ws is poisoned) ----
    {
        int tot1 = 4 * 9 * 8 * 64;
        prep_wfrag<<<(tot1 + 255) / 256, 256, 0, stream>>>(ew1, w1f, 9, 2 * HID + EDIM, tot1);
        int tot2 = 4 * 4 * 8 * 64;
        prep_wfrag<<<(tot2 + 255) / 256, 256, 0, stream>>>(ew2, w2f, 4, HID, tot2);
        int tot3 = 4 * 8 * 8 * 64;
        prep_wfrag<<<(tot3 + 255) / 256, 256, 0, stream>>>(nw, nwf, 8, 2 * HID, tot3);
        int tote = E * EDIM;
        prep_ea<<<(tote + 255) / 256, 256, 0, stream>>>(edge_attr, eab, tote);
    }

    embed_kernel<<<N, HID, 0, stream>>>(z, emb, xb, N);

    for (int l = 0; l < 4; ++l) {
        hipMemsetAsync(agg, 0, (size_t)N * HID * sizeof(float), stream);
        edge_mfma<<<(E + 31) / 32, 256, 0, stream>>>(
            xb, srcI, dstI, eab,
            w1f + (size_t)l * 72 * 512, eb1 + (size_t)l * HID,
            w2f + (size_t)l * 32 * 512, eb2 + (size_t)l * HID,
            agg, E);
        node_mfma<<<(N + 31) / 32, 256, 0, stream>>>(
            xb, agg, nwf + (size_t)l * 64 * 512, nb + (size_t)l * HID, N);
    }

    hipMemsetAsync(sums,   0, (size_t)G * HID * sizeof(float), stream);
    hipMemsetAsync(counts, 0, (size_t)G * sizeof(float), stream);
    segsum_kernel<<<N, HID, 0, stream>>>(xb, batch, sums, counts, N);
    readout_kernel<<<G, HID, 0, stream>>>(sums, counts, rw1, rb1, rw2, rb2, pred);
}